// Round 7
// baseline (800.752 us; speedup 1.0000x reference)
//
#include <hip/hip_runtime.h>
#include <stdint.h>

#define DD 512
#define MTOT 32768  // B*N = 8*4096
#define NBLK 512    // persistent blocks: 2/CU x 256 CU, forced by launch_bounds

typedef float f32x4 __attribute__((ext_vector_type(4)));
typedef __bf16 bf16x8 __attribute__((ext_vector_type(8)));

static __device__ __forceinline__ unsigned short f2bf(float f) {
  union { float f; unsigned int u; } c; c.f = f;
  unsigned int r = c.u + 0x7fffu + ((c.u >> 16) & 1u);
  return (unsigned short)(r >> 16);
}
static __device__ __forceinline__ float bf2f(unsigned short h) {
  union { unsigned int u; float f; } c; c.u = ((unsigned int)h) << 16;
  return c.f;
}

union FragU { uint4 u; bf16x8 b; };

static __device__ __forceinline__ void load_lds16(const void* g, void* l) {
  __builtin_amdgcn_global_load_lds(
      (const __attribute__((address_space(1))) void*)g,
      (__attribute__((address_space(3))) void*)l, 16, 0, 0);
}

// ---- device-scope grid barrier (counter+generation, all blocks resident) --
// bar[0]=arrival counter, bar[1]=generation. Zeroed by hipMemsetAsync.
static __device__ __forceinline__ void grid_bar(unsigned* bar) {
  __syncthreads();
  if (threadIdx.x == 0) {
    unsigned* cnt = bar;
    unsigned* gen = bar + 1;
    __threadfence();  // release prior global writes to device scope
    unsigned g = __hip_atomic_load(gen, __ATOMIC_RELAXED, __HIP_MEMORY_SCOPE_AGENT);
    unsigned a = __hip_atomic_fetch_add(cnt, 1u, __ATOMIC_ACQ_REL, __HIP_MEMORY_SCOPE_AGENT);
    if (a == NBLK - 1) {
      __hip_atomic_store(cnt, 0u, __ATOMIC_RELAXED, __HIP_MEMORY_SCOPE_AGENT);
      __hip_atomic_fetch_add(gen, 1u, __ATOMIC_ACQ_REL, __HIP_MEMORY_SCOPE_AGENT);
    } else {
      while (__hip_atomic_load(gen, __ATOMIC_ACQUIRE, __HIP_MEMORY_SCOPE_AGENT) == g)
        __builtin_amdgcn_s_sleep(2);
    }
    __threadfence();  // acquire side
  }
  __syncthreads();
}

struct MegaP {
  const float *a, *b, *Wq, *bq, *Wk, *bk, *wg, *Wp, *bp, *Wf, *bfb;
  unsigned short *O1b, *Qb, *Kb, *Wqb, *Wkb, *Wfb, *Wps;
  float *ssqQ, *ssqK, *Pd, *G, *qinv, *kinv;
  float *out;
  unsigned* bar;
};

// ---- ph0: weights -> bf16 (768 units; stats zeroed by memset) ------------
static __device__ __forceinline__ void cvt_unit(const MegaP& P, int u) {
  const int tid = threadIdx.x;
  int slab = u >> 8;
  int off = ((u & 255) * 256 + tid) * 4;
  const float* s = slab == 0 ? P.Wq : slab == 1 ? P.Wk : P.Wf;
  unsigned short* d = slab == 0 ? P.Wqb : slab == 1 ? P.Wkb : P.Wfb;
  float4 f = *(const float4*)(s + off);
  ushort4 h;
  h.x = f2bf(f.x); h.y = f2bf(f.y); h.z = f2bf(f.z); h.w = f2bf(f.w);
  *(ushort4*)(d + off) = h;
}

// ---- ph1: merged Q/K GEMM tile, fused fp32->bf16 (r4 structure verbatim) -
// A staged into LDS as RAW fp32 via global_load_lds; converted to bf16 at
// frag-read time. Granule swizzle on the global source; LDS dest linear.
// tile t in [0,2048): swz=(t&7)*256+(t>>3); [0,1024)=Q, [1024,2048)=K.
static __device__ void qk_tile(const MegaP& P, int t, unsigned char* smem) {
  float* AsF = (float*)smem;                             // 32 KB
  unsigned short* Bs = (unsigned short*)(smem + 32768);  // 16 KB
  const int swz = (t & 7) * 256 + (t >> 3);
  const int isK = swz >> 10;
  const int tt = swz & 1023;
  const int row0 = (tt >> 2) * 128, col0 = (tt & 3) * 128;
  const float* X = isK ? P.b : P.a;
  const unsigned short* W = isK ? P.Wkb : P.Wqb;
  const float* bias = isK ? P.bk : P.bq;
  float* ssq = isK ? P.ssqK : P.ssqQ;
  unsigned short* C = isK ? P.Kb : P.Qb;

  const int lane = threadIdx.x & 63, wave = threadIdx.x >> 6;

  // A staging (fp32): 8 instrs/K-step, lane covers row rl of each 4-row slab
  const int rl = lane >> 4;
  const int gsE = (lane & 15) ^ (rl << 1);  // src granule, even q
  const int gsO = gsE ^ 1;                  // src granule, odd q
  const float* AgE = X + (size_t)(row0 + wave * 32 + rl) * DD + gsE * 4;
  const float* AgO = X + (size_t)(row0 + wave * 32 + rl) * DD + gsO * 4;
  const int ldsA = wave * 2048;  // float elems

  // B staging (bf16 global_load_lds, pre-swizzled source)
  const int sr = lane >> 3;
  const int scol = ((lane & 7) ^ sr) * 8;
  const unsigned short* Bg = W + (size_t)(col0 + wave * 32 + sr) * DD + scol;
  const int ldsb = wave * 2048;  // ushort elems

  const int fr = lane & 15, quad = lane >> 4;
  const int wr = (wave >> 1) * 64, wc = (wave & 1) * 64;
  const int xorv = ((fr & 7) >> 2) | ((fr & 3) << 1);
  const int swB0 = ((quad ^ (fr & 7)) * 8);
  const int swB1 = (((quad + 4) ^ (fr & 7)) * 8);

  f32x4 acc[4][4] = {};

  for (int k0 = 0; k0 < DD; k0 += 64) {
#pragma unroll
    for (int q = 0; q < 8; q++) {
      const float* src = ((q & 1) ? AgO : AgE) + (size_t)q * 4 * DD + k0;
      load_lds16(src, AsF + ldsA + q * 256);
    }
#pragma unroll
    for (int q = 0; q < 4; q++)
      load_lds16(Bg + (size_t)q * 8 * DD + k0, Bs + ldsb + q * 512);
    __syncthreads();
#pragma unroll
    for (int kk = 0; kk < 2; kk++) {
      const int glo = ((kk * 4 + quad) * 2) ^ xorv;
      const int ghi = glo ^ 1;
      const int swB = kk ? swB1 : swB0;
      bf16x8 af[4], bfr[4];
#pragma unroll
      for (int i = 0; i < 4; i++) {
        const float* ap = &AsF[(wr + i * 16 + fr) * 64];
        f32x4 lo = *(const f32x4*)(ap + glo * 4);
        f32x4 hi = *(const f32x4*)(ap + ghi * 4);
        bf16x8 v;
        v[0] = (__bf16)lo.x; v[1] = (__bf16)lo.y;
        v[2] = (__bf16)lo.z; v[3] = (__bf16)lo.w;
        v[4] = (__bf16)hi.x; v[5] = (__bf16)hi.y;
        v[6] = (__bf16)hi.z; v[7] = (__bf16)hi.w;
        af[i] = v;
      }
#pragma unroll
      for (int j = 0; j < 4; j++) {
        FragU u; u.u = *(const uint4*)&Bs[(wc + j * 16 + fr) * 64 + swB];
        bfr[j] = u.b;
      }
#pragma unroll
      for (int i = 0; i < 4; i++)
#pragma unroll
        for (int j = 0; j < 4; j++)
          acc[i][j] = __builtin_amdgcn_mfma_f32_16x16x32_bf16(af[i], bfr[j], acc[i][j], 0, 0, 0);
    }
    __syncthreads();
  }

  // epilogue: C/D layout col=lane&15, row=(lane>>4)*4+reg
  const int colbase = col0 + wc + fr;
  float bv4[4], wg4[4];
#pragma unroll
  for (int j = 0; j < 4; j++) bv4[j] = bias[colbase + j * 16];
  if (!isK) {
#pragma unroll
    for (int j = 0; j < 4; j++) wg4[j] = P.wg[colbase + j * 16];
  }
#pragma unroll
  for (int i = 0; i < 4; i++) {
#pragma unroll
    for (int r = 0; r < 4; r++) {
      const int row = row0 + wr + i * 16 + quad * 4 + r;
      float ssum = 0.f, dsum = 0.f;
#pragma unroll
      for (int j = 0; j < 4; j++) {
        size_t idx = (size_t)row * DD + colbase + j * 16;
        float v = acc[i][j][r] + bv4[j];
        C[idx] = f2bf(v);
        ssum += v * v;
        if (!isK) dsum += v * wg4[j];
      }
#pragma unroll
      for (int m = 1; m < 16; m <<= 1) ssum += __shfl_xor(ssum, m, 64);
      if (!isK) {
#pragma unroll
        for (int m = 1; m < 16; m <<= 1) dsum += __shfl_xor(dsum, m, 64);
      }
      if (fr == 0) {
        atomicAdd(&ssq[row], ssum);
        if (!isK) atomicAdd(&P.Pd[row], dsum);
      }
    }
  }
}

// ---- ph2: per-batch sinv + qinv/kinv + learned pooling (512x64-row) ------
static __device__ void pool_unit(const MegaP& P, int u, unsigned char* smem) {
  float* sred = (float*)smem;              // 4 floats
  float* gred = (float*)(smem + 64);       // 4*512 floats (8 KB)
  const int b = u >> 6, chunk = u & 63;
  const int t = threadIdx.x, lane = t & 63, wave = t >> 6;

  float ss = 0.f;
  for (int i = t; i < 4096; i += 256) {
    int n = b * 4096 + i;
    float qi = 1.0f / fmaxf(sqrtf(P.ssqQ[n]), 1e-12f);
    float A = P.Pd[n] * qi;
    ss += A * A;
  }
#pragma unroll
  for (int m = 1; m < 64; m <<= 1) ss += __shfl_xor(ss, m, 64);
  if (lane == 0) sred[wave] = ss;
  if (t < 64) {
    int n = b * 4096 + chunk * 64 + t;
    P.qinv[n] = 1.0f / fmaxf(sqrtf(P.ssqQ[n]), 1e-12f);
    P.kinv[n] = 1.0f / fmaxf(sqrtf(P.ssqK[n]), 1e-12f);
  }
  __syncthreads();
  const float sinv_b =
      1.0f / fmaxf(sqrtf(sred[0] + sred[1] + sred[2] + sred[3]), 1e-12f);

  float acc[8] = {};
  const int r0 = b * 4096 + chunk * 64 + wave * 16;
  for (int r = 0; r < 16; r++) {
    const int n = r0 + r;
    float qi = 1.0f / fmaxf(sqrtf(P.ssqQ[n]), 1e-12f);
    float wrow = P.Pd[n] * qi * qi * sinv_b;
    uint4 uu = *(const uint4*)(P.Qb + (size_t)n * DD + lane * 8);
    const unsigned short* h = (const unsigned short*)&uu;
#pragma unroll
    for (int j = 0; j < 8; j++) acc[j] += wrow * bf2f(h[j]);
  }
#pragma unroll
  for (int j = 0; j < 8; j++) gred[wave * 512 + lane * 8 + j] = acc[j];
  __syncthreads();
  float g0 = gred[t] + gred[512 + t] + gred[1024 + t] + gred[1536 + t];
  float g1 = gred[t + 256] + gred[512 + t + 256] + gred[1024 + t + 256] + gred[1536 + t + 256];
  atomicAdd(&P.G[b * DD + t], g0);
  atomicAdd(&P.G[b * DD + t + 256], g1);
  __syncthreads();  // protect smem before next phase reuses it
}

// ---- ph3: W'p[b] = Wp * G[b,:] ------------------------------------------
static __device__ __forceinline__ void scalew_unit(const MegaP& P, int u) {
  int i = (u * 256 + threadIdx.x) * 4;  // [0, 8*262144)
  int b = i >> 18;
  int rem = i & 262143;
  int d = rem & 511;
  float4 w = *(const float4*)(P.Wp + rem);
  float4 g = *(const float4*)(P.G + b * DD + d);
  ushort4 h;
  h.x = f2bf(w.x * g.x); h.y = f2bf(w.y * g.y);
  h.z = f2bf(w.z * g.z); h.w = f2bf(w.w * g.w);
  *(ushort4*)(P.Wps + i) = h;
}

// ---- shared bf16 GEMM core (m97 structure) -------------------------------
static __device__ __forceinline__ void gemm_core(
    const unsigned short* __restrict__ X, const unsigned short* __restrict__ W,
    int row0, int col0, unsigned short* As, unsigned short* Bs,
    f32x4 (&acc)[4][4]) {
  const int tid = threadIdx.x;
  const int lane = tid & 63, wave = tid >> 6;
  const int sr = lane >> 3;
  const int scol = ((lane & 7) ^ sr) * 8;
  const unsigned short* Ag = X + (size_t)(row0 + wave * 32 + sr) * DD + scol;
  const unsigned short* Bg = W + (size_t)(col0 + wave * 32 + sr) * DD + scol;
  const int ldsb = wave * 2048;
  const int fr = lane & 15, quad = lane >> 4;
  const int wr = (wave >> 1) * 64, wc = (wave & 1) * 64;
  const int sw0 = ((quad ^ (fr & 7)) * 8);
  const int sw1 = (((quad + 4) ^ (fr & 7)) * 8);

  for (int k0 = 0; k0 < DD; k0 += 64) {
#pragma unroll
    for (int q = 0; q < 4; q++) {
      load_lds16(Ag + (size_t)q * 8 * DD + k0, As + ldsb + q * 512);
      load_lds16(Bg + (size_t)q * 8 * DD + k0, Bs + ldsb + q * 512);
    }
    __syncthreads();
#pragma unroll
    for (int kk = 0; kk < 2; kk++) {
      const int sw = kk ? sw1 : sw0;
      bf16x8 af[4], bfr[4];
#pragma unroll
      for (int i = 0; i < 4; i++) {
        FragU u; u.u = *(const uint4*)&As[(wr + i * 16 + fr) * 64 + sw];
        af[i] = u.b;
      }
#pragma unroll
      for (int j = 0; j < 4; j++) {
        FragU u; u.u = *(const uint4*)&Bs[(wc + j * 16 + fr) * 64 + sw];
        bfr[j] = u.b;
      }
#pragma unroll
      for (int i = 0; i < 4; i++)
#pragma unroll
        for (int j = 0; j < 4; j++)
          acc[i][j] = __builtin_amdgcn_mfma_f32_16x16x32_bf16(af[i], bfr[j], acc[i][j], 0, 0, 0);
    }
    __syncthreads();
  }
}

// ---- ph4/ph5: bf16 GEMMs with scalar-folded epilogues --------------------
// EMODE 3: kinv*acc + bias + qinv*Qadd -> bf16 (P GEMM, per-batch W)
// EMODE 4: acc + bias -> fp32 (final GEMM)
template<int EMODE>
static __device__ void gemm_tile(const MegaP& P, int t, unsigned char* smem) {
  unsigned short* As = (unsigned short*)smem;
  unsigned short* Bs = (unsigned short*)(smem + 16384);
  const int swz = (t & 7) * 128 + (t >> 3);
  const int row0 = (swz >> 2) * 128, col0 = (swz & 3) * 128;
  const unsigned short* X = (EMODE == 3) ? P.Kb : P.O1b;
  const unsigned short* W = (EMODE == 3)
      ? P.Wps + (size_t)(row0 >> 12) * 262144 : P.Wfb;
  const float* bias = (EMODE == 3) ? P.bp : P.bfb;

  f32x4 acc[4][4] = {};
  gemm_core(X, W, row0, col0, As, Bs, acc);

  const int lane = threadIdx.x & 63, wave = threadIdx.x >> 6;
  const int fr = lane & 15, quad = lane >> 4;
  const int wr = (wave >> 1) * 64, wc = (wave & 1) * 64;
  const int colbase = col0 + wc + fr;
  float bv4[4];
#pragma unroll
  for (int j = 0; j < 4; j++) bv4[j] = bias[colbase + j * 16];
#pragma unroll
  for (int i = 0; i < 4; i++) {
#pragma unroll
    for (int r = 0; r < 4; r++) {
      const int row = row0 + wr + i * 16 + quad * 4 + r;
      float ki = 1.f, qi = 1.f;
      if (EMODE == 3) { ki = P.kinv[row]; qi = P.qinv[row]; }
#pragma unroll
      for (int j = 0; j < 4; j++) {
        size_t idx = (size_t)row * DD + colbase + j * 16;
        if (EMODE == 3) {
          float v = acc[i][j][r] * ki + bv4[j] + qi * bf2f(P.Qb[idx]);
          P.O1b[idx] = f2bf(v);
        } else {
          P.out[idx] = acc[i][j][r] + bv4[j];
        }
      }
    }
  }
  __syncthreads();  // protect smem before next tile restages
}

// ---------------- the persistent mega-kernel (plain launch) ---------------
__global__ __launch_bounds__(256, 2) void mega_k(MegaP P) {
  __shared__ __align__(16) unsigned char smem[49152];
  const int bid = blockIdx.x;

  // ph0: weight cvt (stats zeroed by host-side memset)
  for (int u = bid; u < 768; u += NBLK) cvt_unit(P, u);
  grid_bar(P.bar);
  // ph1: Q/K GEMMs, fused fp32->bf16 (2048 tiles)
#pragma unroll 1
  for (int i = 0; i < 4; i++) qk_tile(P, bid + NBLK * i, smem);
  grid_bar(P.bar);
  // ph2: pooling stats + G (512 units)
  pool_unit(P, bid, smem);
  grid_bar(P.bar);
  // ph3: Wps = Wp * G[b] (2048 units)
#pragma unroll 1
  for (int i = 0; i < 4; i++) scalew_unit(P, bid + NBLK * i);
  grid_bar(P.bar);
  // ph4: O1 = kinv*(K*(Wp.G)^T) + bp + qinv*Q (1024 tiles)
#pragma unroll 1
  for (int i = 0; i < 2; i++) gemm_tile<3>(P, bid + NBLK * i, smem);
  grid_bar(P.bar);
  // ph5: out = O1*Wf^T + bf, fp32 (1024 tiles)
#pragma unroll 1
  for (int i = 0; i < 2; i++) gemm_tile<4>(P, bid + NBLK * i, smem);
}

extern "C" void kernel_launch(void* const* d_in, const int* in_sizes, int n_in,
                              void* d_out, int out_size, void* d_ws, size_t ws_size,
                              hipStream_t stream) {
  const size_t WELEM = 262144;          // 512*512
  const size_t MD = (size_t)MTOT * DD;  // 16,777,216 elems

  unsigned short* O1b = (unsigned short*)d_ws;
  unsigned short* Qb  = O1b + MD;
  unsigned short* Kb  = Qb + MD;
  unsigned short* Wqb = Kb + MD;
  unsigned short* Wkb = Wqb + WELEM;
  unsigned short* Wfb = Wkb + WELEM;
  unsigned short* Wps = Wfb + WELEM;            // 8 * 262144
  float* stats = (float*)(Wps + 8 * WELEM);

  MegaP P;
  P.a   = (const float*)d_in[0];
  P.b   = (const float*)d_in[1];
  P.Wq  = (const float*)d_in[2];
  P.bq  = (const float*)d_in[3];
  P.Wk  = (const float*)d_in[4];
  P.bk  = (const float*)d_in[5];
  P.wg  = (const float*)d_in[6];
  P.Wp  = (const float*)d_in[7];
  P.bp  = (const float*)d_in[8];
  P.Wf  = (const float*)d_in[9];
  P.bfb = (const float*)d_in[10];
  P.O1b = O1b; P.Qb = Qb; P.Kb = Kb;
  P.Wqb = Wqb; P.Wkb = Wkb; P.Wfb = Wfb; P.Wps = Wps;
  P.ssqQ = stats;                // [MTOT]
  P.ssqK = stats + MTOT;         // [MTOT]
  P.Pd   = stats + 2 * MTOT;     // [MTOT]
  P.G    = stats + 3 * MTOT;     // [8*512]
  P.bar  = (unsigned*)(P.G + 4096);       // 2 words
  P.qinv = (float*)(P.bar + 2);
  P.kinv = P.qinv + MTOT;
  P.out  = (float*)d_out;

  // zero ssqQ/ssqK/Pd/G (102400 floats) + barrier words (2 uints)
  hipMemsetAsync(stats, 0, 102400 * sizeof(float) + 2 * sizeof(unsigned), stream);
  mega_k<<<dim3(NBLK), dim3(256), 0, stream>>>(P);
}

// Round 8
// 336.829 us; speedup vs baseline: 2.3773x; 2.3773x over previous
//
#include <hip/hip_runtime.h>
#include <stdint.h>

#define DD 512
#define MTOT 32768  // B*N = 8*4096

typedef float f32x4 __attribute__((ext_vector_type(4)));
typedef __bf16 bf16x8 __attribute__((ext_vector_type(8)));

static __device__ __forceinline__ unsigned short f2bf(float f) {
  union { float f; unsigned int u; } c; c.f = f;
  unsigned int r = c.u + 0x7fffu + ((c.u >> 16) & 1u);
  return (unsigned short)(r >> 16);
}
static __device__ __forceinline__ float bf2f(unsigned short h) {
  union { unsigned int u; float f; } c; c.u = ((unsigned int)h) << 16;
  return c.f;
}

union FragU { uint4 u; bf16x8 b; };

static __device__ __forceinline__ void load_lds16(const void* g, void* l) {
  __builtin_amdgcn_global_load_lds(
      (const __attribute__((address_space(1))) void*)g,
      (__attribute__((address_space(3))) void*)l, 16, 0, 0);
}

// ---- weights -> bf16, Wp^T -> bf16 (LDS transpose), zero stats -----------
// blocks [0,768): Wq/Wk/Wf cvt. [768,832): WpT 64x64 tiles. [832,932): zero.
__global__ __launch_bounds__(256) void cvt3w_k(const float* __restrict__ W0,
    const float* __restrict__ W1, const float* __restrict__ W2,
    const float* __restrict__ Wp,
    unsigned short* __restrict__ D0, unsigned short* __restrict__ D1,
    unsigned short* __restrict__ D2, unsigned short* __restrict__ WpT,
    float* __restrict__ stats) {
  __shared__ float tl[64][65];
  const int u = blockIdx.x, t = threadIdx.x;
  if (u < 768) {
    int slab = u >> 8;
    int off = ((u & 255) * 256 + t) * 4;
    const float* s = slab == 0 ? W0 : slab == 1 ? W1 : W2;
    unsigned short* d = slab == 0 ? D0 : slab == 1 ? D1 : D2;
    float4 f = *(const float4*)(s + off);
    ushort4 h;
    h.x = f2bf(f.x); h.y = f2bf(f.y); h.z = f2bf(f.z); h.w = f2bf(f.w);
    *(ushort4*)(d + off) = h;
  } else if (u < 832) {
    const int tile = u - 768, tr = tile >> 3, tc = tile & 7;
    const int r = t >> 2, cq = t & 3;
    const float* src = Wp + (size_t)(tr * 64 + r) * 512 + tc * 64 + cq * 16;
#pragma unroll
    for (int i = 0; i < 4; i++) {
      float4 v = ((const float4*)src)[i];
      tl[r][cq * 16 + i * 4 + 0] = v.x; tl[r][cq * 16 + i * 4 + 1] = v.y;
      tl[r][cq * 16 + i * 4 + 2] = v.z; tl[r][cq * 16 + i * 4 + 3] = v.w;
    }
    __syncthreads();
    unsigned short* dst = WpT + (size_t)(tc * 64 + r) * 512 + tr * 64 + cq * 16;
#pragma unroll
    for (int i = 0; i < 4; i++) {
      ushort4 h;
      h.x = f2bf(tl[cq * 16 + i * 4 + 0][r]);
      h.y = f2bf(tl[cq * 16 + i * 4 + 1][r]);
      h.z = f2bf(tl[cq * 16 + i * 4 + 2][r]);
      h.w = f2bf(tl[cq * 16 + i * 4 + 3][r]);
      ((ushort4*)dst)[i] = h;
    }
  } else {
    int i = ((u - 832) * 256 + t) * 4;  // [0, 102400) = ssqQ,ssqK,Pd,G
    *(float4*)(stats + i) = make_float4(0.f, 0.f, 0.f, 0.f);
  }
}

// ---------------- shared bf16 GEMM core (m97 structure) -------------------
// 128x128 tile, BK=64, global_load_lds width-16, XOR-swizzle kseg^(row&7).
static __device__ __forceinline__ void gemm_core(
    const unsigned short* __restrict__ X, const unsigned short* __restrict__ W,
    int row0, int col0, unsigned short* As, unsigned short* Bs,
    f32x4 (&acc)[4][4]) {
  const int tid = threadIdx.x;
  const int lane = tid & 63, wave = tid >> 6;
  const int sr = lane >> 3;
  const int scol = ((lane & 7) ^ sr) * 8;
  const unsigned short* Ag = X + (size_t)(row0 + wave * 32 + sr) * DD + scol;
  const unsigned short* Bg = W + (size_t)(col0 + wave * 32 + sr) * DD + scol;
  const int ldsb = wave * 2048;
  const int fr = lane & 15, quad = lane >> 4;
  const int wr = (wave >> 1) * 64, wc = (wave & 1) * 64;
  const int sw0 = ((quad ^ (fr & 7)) * 8);
  const int sw1 = (((quad + 4) ^ (fr & 7)) * 8);

  for (int k0 = 0; k0 < DD; k0 += 64) {
#pragma unroll
    for (int q = 0; q < 4; q++) {
      load_lds16(Ag + (size_t)q * 8 * DD + k0, As + ldsb + q * 512);
      load_lds16(Bg + (size_t)q * 8 * DD + k0, Bs + ldsb + q * 512);
    }
    __syncthreads();
#pragma unroll
    for (int kk = 0; kk < 2; kk++) {
      const int sw = kk ? sw1 : sw0;
      bf16x8 af[4], bfr[4];
#pragma unroll
      for (int i = 0; i < 4; i++) {
        FragU u; u.u = *(const uint4*)&As[(wr + i * 16 + fr) * 64 + sw];
        af[i] = u.b;
      }
#pragma unroll
      for (int j = 0; j < 4; j++) {
        FragU u; u.u = *(const uint4*)&Bs[(wc + j * 16 + fr) * 64 + sw];
        bfr[j] = u.b;
      }
#pragma unroll
      for (int i = 0; i < 4; i++)
#pragma unroll
        for (int j = 0; j < 4; j++)
          acc[i][j] = __builtin_amdgcn_mfma_f32_16x16x32_bf16(af[i], bfr[j], acc[i][j], 0, 0, 0);
    }
    __syncthreads();
  }
}

// ---- F = Wf*Wp (blocks 0..15) ; bconst = Wf*bp + bf (blocks 16..19) ------
__global__ __launch_bounds__(256) void fgemm_k(
    const unsigned short* __restrict__ Wfb, const unsigned short* __restrict__ WpT,
    const float* __restrict__ Wf, const float* __restrict__ bp,
    const float* __restrict__ bfb, unsigned short* __restrict__ Fb,
    float* __restrict__ bconst) {
  const int bb = blockIdx.x, t = threadIdx.x;
  if (bb >= 16) {
    const int j = (bb - 16) * 128 + (t >> 1), half = t & 1;
    float s = 0.f;
    const float* wr = Wf + (size_t)j * 512 + half * 256;
    const float* bpr = bp + half * 256;
    for (int n = 0; n < 256; n++) s += wr[n] * bpr[n];
    s += __shfl_xor(s, 1, 64);
    if (half == 0) bconst[j] = s + bfb[j];
    return;
  }
  __shared__ unsigned short As[128 * 64];
  __shared__ unsigned short Bs[128 * 64];
  const int row0 = (bb >> 2) * 128, col0 = (bb & 3) * 128;
  f32x4 acc[4][4] = {};
  gemm_core(Wfb, WpT, row0, col0, As, Bs, acc);
  const int lane = t & 63, wave = t >> 6;
  const int fr = lane & 15, quad = lane >> 4;
  const int wr = (wave >> 1) * 64, wc = (wave & 1) * 64;
#pragma unroll
  for (int i = 0; i < 4; i++)
#pragma unroll
    for (int r = 0; r < 4; r++) {
      const int row = row0 + wr + i * 16 + quad * 4 + r;
#pragma unroll
      for (int j = 0; j < 4; j++)
        Fb[(size_t)row * 512 + col0 + wc + j * 16 + fr] = f2bf(acc[i][j][r]);
    }
}

// ---- Mb[b][j,k] = F[j,k] * G[b,k] ----------------------------------------
__global__ __launch_bounds__(256) void mscale_k(const unsigned short* __restrict__ Fb,
    const float* __restrict__ G, unsigned short* __restrict__ Mb) {
  int i = (blockIdx.x * 256 + threadIdx.x) * 4;  // [0, 8*262144)
  int b = i >> 18;
  int rem = i & 262143;
  int k = rem & 511;
  ushort4 f = *(const ushort4*)(Fb + rem);
  float4 g = *(const float4*)(G + b * DD + k);
  ushort4 h;
  h.x = f2bf(bf2f(f.x) * g.x); h.y = f2bf(bf2f(f.y) * g.y);
  h.z = f2bf(bf2f(f.z) * g.z); h.w = f2bf(bf2f(f.w) * g.w);
  *(ushort4*)(Mb + i) = h;
}

// --------- merged Q/K GEMM with fp32 A operand (r4 verbatim) --------------
// A staged into LDS as RAW fp32 via global_load_lds; converted to bf16 at
// frag-read time. Granule swizzle on the global source; LDS dest linear.
// blocks: swz [0,1024) = Q (a*Wq^T+bq, +ssq +wg-dot), [1024,2048) = K.
__global__ __launch_bounds__(256) void gemm_qk_k(
    const float* __restrict__ Xa, const float* __restrict__ Xb,
    const unsigned short* __restrict__ Wqw, const unsigned short* __restrict__ Wkw,
    const float* __restrict__ bq, const float* __restrict__ bk,
    const float* __restrict__ wg,
    float* __restrict__ ssqQ, float* __restrict__ ssqK, float* __restrict__ Pdot,
    unsigned short* __restrict__ Cq, unsigned short* __restrict__ Ck) {
  __shared__ float AsF[128 * 64];          // 32 KB
  __shared__ unsigned short Bs[128 * 64];  // 16 KB
  const int swz = (blockIdx.x & 7) * 256 + (blockIdx.x >> 3);
  const int isK = swz >> 10;
  const int tt = swz & 1023;
  const int row0 = (tt >> 2) * 128, col0 = (tt & 3) * 128;
  const float* X = isK ? Xb : Xa;
  const unsigned short* W = isK ? Wkw : Wqw;
  const float* bias = isK ? bk : bq;
  float* ssq = isK ? ssqK : ssqQ;
  unsigned short* C = isK ? Ck : Cq;

  const int lane = threadIdx.x & 63, wave = threadIdx.x >> 6;

  const int rl = lane >> 4;
  const int gsE = (lane & 15) ^ (rl << 1);
  const int gsO = gsE ^ 1;
  const float* AgE = X + (size_t)(row0 + wave * 32 + rl) * DD + gsE * 4;
  const float* AgO = X + (size_t)(row0 + wave * 32 + rl) * DD + gsO * 4;
  const int ldsA = wave * 2048;

  const int sr = lane >> 3;
  const int scol = ((lane & 7) ^ sr) * 8;
  const unsigned short* Bg = W + (size_t)(col0 + wave * 32 + sr) * DD + scol;
  const int ldsb = wave * 2048;

  const int fr = lane & 15, quad = lane >> 4;
  const int wr = (wave >> 1) * 64, wc = (wave & 1) * 64;
  const int xorv = ((fr & 7) >> 2) | ((fr & 3) << 1);
  const int swB0 = ((quad ^ (fr & 7)) * 8);
  const int swB1 = (((quad + 4) ^ (fr & 7)) * 8);

  f32x4 acc[4][4] = {};

  for (int k0 = 0; k0 < DD; k0 += 64) {
#pragma unroll
    for (int q = 0; q < 8; q++) {
      const float* src = ((q & 1) ? AgO : AgE) + (size_t)q * 4 * DD + k0;
      load_lds16(src, AsF + ldsA + q * 256);
    }
#pragma unroll
    for (int q = 0; q < 4; q++)
      load_lds16(Bg + (size_t)q * 8 * DD + k0, Bs + ldsb + q * 512);
    __syncthreads();
#pragma unroll
    for (int kk = 0; kk < 2; kk++) {
      const int glo = ((kk * 4 + quad) * 2) ^ xorv;
      const int ghi = glo ^ 1;
      const int swB = kk ? swB1 : swB0;
      bf16x8 af[4], bfr[4];
#pragma unroll
      for (int i = 0; i < 4; i++) {
        const float* ap = &AsF[(wr + i * 16 + fr) * 64];
        f32x4 lo = *(const f32x4*)(ap + glo * 4);
        f32x4 hi = *(const f32x4*)(ap + ghi * 4);
        bf16x8 v;
        v[0] = (__bf16)lo.x; v[1] = (__bf16)lo.y;
        v[2] = (__bf16)lo.z; v[3] = (__bf16)lo.w;
        v[4] = (__bf16)hi.x; v[5] = (__bf16)hi.y;
        v[6] = (__bf16)hi.z; v[7] = (__bf16)hi.w;
        af[i] = v;
      }
#pragma unroll
      for (int j = 0; j < 4; j++) {
        FragU u; u.u = *(const uint4*)&Bs[(wc + j * 16 + fr) * 64 + swB];
        bfr[j] = u.b;
      }
#pragma unroll
      for (int i = 0; i < 4; i++)
#pragma unroll
        for (int j = 0; j < 4; j++)
          acc[i][j] = __builtin_amdgcn_mfma_f32_16x16x32_bf16(af[i], bfr[j], acc[i][j], 0, 0, 0);
    }
    __syncthreads();
  }

  const int colbase = col0 + wc + fr;
  float bv4[4], wg4[4];
#pragma unroll
  for (int j = 0; j < 4; j++) bv4[j] = bias[colbase + j * 16];
  if (!isK) {
#pragma unroll
    for (int j = 0; j < 4; j++) wg4[j] = wg[colbase + j * 16];
  }
#pragma unroll
  for (int i = 0; i < 4; i++) {
#pragma unroll
    for (int r = 0; r < 4; r++) {
      const int row = row0 + wr + i * 16 + quad * 4 + r;
      float ssum = 0.f, dsum = 0.f;
#pragma unroll
      for (int j = 0; j < 4; j++) {
        size_t idx = (size_t)row * DD + colbase + j * 16;
        float v = acc[i][j][r] + bv4[j];
        C[idx] = f2bf(v);
        ssum += v * v;
        if (!isK) dsum += v * wg4[j];
      }
#pragma unroll
      for (int m = 1; m < 16; m <<= 1) ssum += __shfl_xor(ssum, m, 64);
      if (!isK) {
#pragma unroll
        for (int m = 1; m < 16; m <<= 1) dsum += __shfl_xor(dsum, m, 64);
      }
      if (fr == 0) {
        atomicAdd(&ssq[row], ssum);
        if (!isK) atomicAdd(&Pdot[row], dsum);
      }
    }
  }
}

// ------- merged finstat+pool (r4 verbatim) --------------------------------
__global__ __launch_bounds__(256) void pool2_k(
    const float* __restrict__ ssqQ, const float* __restrict__ ssqK,
    const float* __restrict__ P, float* __restrict__ qinv,
    float* __restrict__ kinv, const unsigned short* __restrict__ Q,
    float* __restrict__ G) {
  const int b = blockIdx.x >> 5, chunk = blockIdx.x & 31;
  const int t = threadIdx.x, lane = t & 63, wave = t >> 6;
  __shared__ float sred[4];
  __shared__ float gred[4][512];

  float ss = 0.f;
  for (int i = t; i < 4096; i += 256) {
    int n = b * 4096 + i;
    float qi = 1.0f / fmaxf(sqrtf(ssqQ[n]), 1e-12f);
    float A = P[n] * qi;
    ss += A * A;
  }
#pragma unroll
  for (int m = 1; m < 64; m <<= 1) ss += __shfl_xor(ss, m, 64);
  if (lane == 0) sred[wave] = ss;
  if (t < 128) {
    int n = b * 4096 + chunk * 128 + t;
    qinv[n] = 1.0f / fmaxf(sqrtf(ssqQ[n]), 1e-12f);
    kinv[n] = 1.0f / fmaxf(sqrtf(ssqK[n]), 1e-12f);
  }
  __syncthreads();
  const float sinv_b =
      1.0f / fmaxf(sqrtf(sred[0] + sred[1] + sred[2] + sred[3]), 1e-12f);

  float acc[8] = {};
  const int r0 = b * 4096 + chunk * 128 + wave * 32;
  for (int r = 0; r < 32; r++) {
    const int n = r0 + r;
    float qi = 1.0f / fmaxf(sqrtf(ssqQ[n]), 1e-12f);
    float wrow = P[n] * qi * qi * sinv_b;
    uint4 u = *(const uint4*)(Q + (size_t)n * DD + lane * 8);
    const unsigned short* h = (const unsigned short*)&u;
#pragma unroll
    for (int j = 0; j < 8; j++) acc[j] += wrow * bf2f(h[j]);
  }
#pragma unroll
  for (int j = 0; j < 8; j++) gred[wave][lane * 8 + j] = acc[j];
  __syncthreads();
  float g0 = gred[0][t] + gred[1][t] + gred[2][t] + gred[3][t];
  float g1 = gred[0][t + 256] + gred[1][t + 256] + gred[2][t + 256] + gred[3][t + 256];
  atomicAdd(&G[b * DD + t], g0);
  atomicAdd(&G[b * DD + t + 256], g1);
}

// ---- fused final: out = kinv*(K*Mb^T) + qinv*(Q*Wf^T) + bconst (fp32) ----
// Two gemm_core passes sharing one output tile; XCD-chunked swizzle.
__global__ __launch_bounds__(256) void final_k(
    const unsigned short* __restrict__ Kb, const unsigned short* __restrict__ Qb,
    const unsigned short* __restrict__ Mb, const unsigned short* __restrict__ Wfb,
    const float* __restrict__ bconst,
    const float* __restrict__ qinv, const float* __restrict__ kinv,
    float* __restrict__ out) {
  __shared__ unsigned short As[128 * 64];
  __shared__ unsigned short Bs[128 * 64];
  const int swz = (blockIdx.x & 7) * 128 + (blockIdx.x >> 3);
  const int row0 = (swz >> 2) * 128, col0 = (swz & 3) * 128;
  const unsigned short* M = Mb + (size_t)(row0 >> 12) * 262144;

  f32x4 accK[4][4] = {};
  gemm_core(Kb, M, row0, col0, As, Bs, accK);
  f32x4 accQ[4][4] = {};
  gemm_core(Qb, Wfb, row0, col0, As, Bs, accQ);

  const int lane = threadIdx.x & 63, wave = threadIdx.x >> 6;
  const int fr = lane & 15, quad = lane >> 4;
  const int wr = (wave >> 1) * 64, wc = (wave & 1) * 64;
  const int colbase = col0 + wc + fr;
  float bv4[4];
#pragma unroll
  for (int j = 0; j < 4; j++) bv4[j] = bconst[colbase + j * 16];
#pragma unroll
  for (int i = 0; i < 4; i++) {
#pragma unroll
    for (int r = 0; r < 4; r++) {
      const int row = row0 + wr + i * 16 + quad * 4 + r;
      const float ki = kinv[row], qi = qinv[row];
#pragma unroll
      for (int j = 0; j < 4; j++) {
        size_t idx = (size_t)row * DD + colbase + j * 16;
        out[idx] = accK[i][j][r] * ki + accQ[i][j][r] * qi + bv4[j];
      }
    }
  }
}

extern "C" void kernel_launch(void* const* d_in, const int* in_sizes, int n_in,
                              void* d_out, int out_size, void* d_ws, size_t ws_size,
                              hipStream_t stream) {
  const float* a   = (const float*)d_in[0];
  const float* b   = (const float*)d_in[1];
  const float* Wq  = (const float*)d_in[2];
  const float* bq  = (const float*)d_in[3];
  const float* Wk  = (const float*)d_in[4];
  const float* bk  = (const float*)d_in[5];
  const float* wg  = (const float*)d_in[6];
  const float* Wp  = (const float*)d_in[7];
  const float* bp  = (const float*)d_in[8];
  const float* Wf  = (const float*)d_in[9];
  const float* bfb = (const float*)d_in[10];

  const size_t WELEM = 262144;          // 512*512
  const size_t MD = (size_t)MTOT * DD;  // 16,777,216 elems

  unsigned short* Qb  = (unsigned short*)d_ws;  // raw Q (bf16)
  unsigned short* Kb  = Qb + MD;                // raw K (bf16)
  unsigned short* Wqb = Kb + MD;
  unsigned short* Wkb = Wqb + WELEM;
  unsigned short* Wfb = Wkb + WELEM;
  unsigned short* WpT = Wfb + WELEM;            // Wp^T bf16
  unsigned short* Fb  = WpT + WELEM;            // F = Wf*Wp bf16
  unsigned short* Mb  = Fb + WELEM;             // 8 * 262144 (F scaled by G[b])
  float* stats = (float*)(Mb + 8 * WELEM);
  float* ssqQ  = stats;                 // [MTOT]   zeroed by cvt3w_k
  float* ssqK  = stats + MTOT;          // [MTOT]   zeroed by cvt3w_k
  float* Pd    = stats + 2 * MTOT;      // [MTOT]   zeroed by cvt3w_k
  float* G     = stats + 3 * MTOT;      // [8*512]  zeroed by cvt3w_k
  float* qinv  = G + 4096;
  float* kinv  = qinv + MTOT;
  float* bconst = kinv + MTOT;          // [512]

  // weights -> bf16 (+WpT transpose); zero stats+G
  cvt3w_k<<<dim3(932), dim3(256), 0, stream>>>(
      Wq, Wk, Wf, Wp, Wqb, Wkb, Wfb, WpT, stats);
  // F = Wf*Wp (bf16); bconst = Wf*bp + bf (fp32)
  fgemm_k<<<dim3(20), dim3(256), 0, stream>>>(Wfb, WpT, Wf, bp, bfb, Fb, bconst);
  // Q = a*Wq^T+bq (+ssqQ, Pdot); K = b*Wk^T+bk (+ssqK); fp32 A fused cvt
  gemm_qk_k<<<dim3(2048), dim3(256), 0, stream>>>(
      a, b, Wqb, Wkb, bq, bk, wg, ssqQ, ssqK, Pd, Qb, Kb);
  // qinv/kinv + per-batch sinv + learned pooling -> G
  pool2_k<<<dim3(256), dim3(256), 0, stream>>>(ssqQ, ssqK, Pd, qinv, kinv, Qb, G);
  // Mb[b] = F .* G[b] (per-column)
  mscale_k<<<dim3(2048), dim3(256), 0, stream>>>(Fb, G, Mb);
  // out = kinv*(K*Mb^T) + qinv*(Q*Wf^T) + bconst
  final_k<<<dim3(1024), dim3(256), 0, stream>>>(
      Kb, Qb, Mb, Wfb, bconst, qinv, kinv, (float*)d_out);
}